// Round 18
// baseline (749.031 us; speedup 1.0000x reference)
//
#include <hip/hip_runtime.h>
#include <hip/hip_cooperative_groups.h>

namespace cg = cooperative_groups;

#define F_DIM 128
#define NG 3
#define AEPT 16
#define CAP 48
#define MAXBIN 256
#define SPILL_CAP 8192

typedef __attribute__((ext_vector_type(8))) short short8_t;
typedef __attribute__((ext_vector_type(4))) float f32x4;
typedef _Float16 h2 __attribute__((ext_vector_type(2)));

__device__ __forceinline__ unsigned short f2bf(float f) {
    unsigned int x = __float_as_uint(f);
    unsigned int r = x + 0x7fffu + ((x >> 16) & 1u);
    return (unsigned short)(r >> 16);
}

__device__ __forceinline__ short8_t cvt8(float4 x0, float4 x1) {
    union { short8_t s; uint4 u; } pk;
    pk.u.x = (unsigned)f2bf(x0.x) | ((unsigned)f2bf(x0.y) << 16);
    pk.u.y = (unsigned)f2bf(x0.z) | ((unsigned)f2bf(x0.w) << 16);
    pk.u.z = (unsigned)f2bf(x1.x) | ((unsigned)f2bf(x1.y) << 16);
    pk.u.w = (unsigned)f2bf(x1.z) | ((unsigned)f2bf(x1.w) << 16);
    return pk.s;
}

struct GArgs {
    const int* src[NG]; const int* dst[NG];
    const float* X[NG]; const float* W[NG]; const float* b[NG];
    float* out[NG];
    unsigned short* Xps[NG];
    unsigned short* sorted[NG];
    unsigned short* Wtb[NG];
    int* binbuf[NG];
    int* bincur[NG];
    int* cstore[NG];
    float* dinv[NG];
    int* spill[NG];
    int* spill_n[NG];
    int nbin, bincap;
};

// ================= device phase units (shared by mega + fallback) =============

__device__ __forceinline__ void init_unit(const GArgs& a, int g, int i) {
    // i in [0, max(nbin, 2048)): bincur + Wtb + spill_n
    if (i < a.nbin) a.bincur[g][i] = i * a.bincap;
    if (i == 0) a.spill_n[g][0] = 0;
    if (i < 2048) {
        int kg = i >> 7, c = i & 127;
        const float* wp = a.W[g] + (size_t)(kg * 8) * F_DIM + c;
        uint4 pk;
        pk.x = (unsigned)f2bf(wp[0])   | ((unsigned)f2bf(wp[128]) << 16);
        pk.y = (unsigned)f2bf(wp[256]) | ((unsigned)f2bf(wp[384]) << 16);
        pk.z = (unsigned)f2bf(wp[512]) | ((unsigned)f2bf(wp[640]) << 16);
        pk.w = (unsigned)f2bf(wp[768]) | ((unsigned)f2bf(wp[896]) << 16);
        *(uint4*)(a.Wtb[g] + (size_t)i * 8) = pk;
    }
}

__device__ void binA_unit(const GArgs& a, int g, int chunk, int E) {
    __shared__ int cnt[MAXBIN];
    __shared__ int lcur[MAXBIN];
    const int t = threadIdx.x;
    const int nbin = a.nbin, bincap = a.bincap;
    for (int i = t; i < nbin; i += 256) cnt[i] = 0;
    __syncthreads();
    const int* dst = a.dst[g];
    const int* src = a.src[g];
    const int base = chunk * (256 * AEPT) + t;
    int dd[AEPT], sv[AEPT];
#pragma unroll
    for (int i = 0; i < AEPT; ++i) {
        int e = base + i * 256;
        int ec = (e < E) ? e : 0;
        dd[i] = __builtin_nontemporal_load(&dst[ec]);
        sv[i] = __builtin_nontemporal_load(&src[ec]);
        if (e < E) atomicAdd(&cnt[dd[i] >> 8], 1);
    }
    __syncthreads();
    for (int i = t; i < nbin; i += 256) {
        int c = cnt[i];
        lcur[i] = c ? atomicAdd(&a.bincur[g][i], c) : 0;
    }
    __syncthreads();
    int* binbuf = a.binbuf[g];
#pragma unroll
    for (int i = 0; i < AEPT; ++i) {
        int e = base + i * 256;
        if (e < E) {
            int bin = dd[i] >> 8;
            int pos = atomicAdd(&lcur[bin], 1);
            if (pos < (bin + 1) * bincap) {
                binbuf[pos] = ((dd[i] & 255) << 16) | sv[i];
            } else {
                int sp = atomicAdd(a.spill_n[g], 1);
                if (sp < SPILL_CAP) {
                    a.spill[g][2 * sp] = sv[i];
                    a.spill[g][2 * sp + 1] = dd[i];
                }
            }
        }
    }
    __syncthreads();  // protect LDS reuse across unit iterations
}

__device__ void binB_unit(const GArgs& a, int g, int bin, int n) {
    __shared__ int cnt[256];
    const int t = threadIdx.x;
    cnt[t] = 0;
    __syncthreads();
    const int bincap = a.bincap;
    int used = a.bincur[g][bin] - bin * bincap;
    int rd = min(used, bincap);
    const int* bb = a.binbuf[g] + bin * bincap;
    unsigned short* sorted = a.sorted[g];
    for (int j = t; j < rd; j += 256) {
        int u = bb[j];
        int dl = u >> 16;
        int s = u & 0xffff;
        int tk = atomicAdd(&cnt[dl], 1);
        int d = (bin << 8) + dl;
        if (tk < CAP) {
            sorted[d * CAP + tk] = (unsigned short)s;
        } else {
            int sp = atomicAdd(a.spill_n[g], 1);
            if (sp < SPILL_CAP) {
                a.spill[g][2 * sp] = s;
                a.spill[g][2 * sp + 1] = d;
            }
        }
    }
    __syncthreads();
    int d = (bin << 8) + t;
    if (d < n) {
        int deg = cnt[t];
        a.cstore[g][d] = min(deg, CAP);
        a.dinv[g][d] = rsqrtf((float)deg + 1.0f);
    }
    __syncthreads();  // protect LDS reuse across unit iterations
}

// 64x64 block tile, 4 waves 2x2, wave tile 32x32 -> ~58 VGPR (fits 64-cap)
__device__ __forceinline__ void gemm_unit(const GArgs& a, int g, int tile, int n) {
    const int t = threadIdx.x;
    int tr = tile >> 1, tc = tile & 1;
    const int l = t & 63, wv = t >> 6;
    const int wr = wv >> 1, wc = wv & 1;
    const int lm = l & 15, lk = l >> 4;
    const int rowA = tr * 64 + wr * 32 + lm;
    const float* X = a.X[g];
    const unsigned short* Wtb = a.Wtb[g];
    f32x4 acc[2][2] = {};
#pragma unroll
    for (int ks = 0; ks < 4; ++ks) {
        short8_t bv[2];
#pragma unroll
        for (int nt = 0; nt < 2; ++nt) {
            int col = tc * 64 + wc * 32 + nt * 16 + lm;
            bv[nt] = *(const short8_t*)(Wtb + ((size_t)((ks * 4 + lk) * 128 + col)) * 8);
        }
#pragma unroll
        for (int mt = 0; mt < 2; ++mt) {
            int row = rowA + mt * 16;
            row = row < n ? row : n - 1;
            const float4* xp = (const float4*)(X + (size_t)row * F_DIM + ks * 32 + lk * 8);
            short8_t af = cvt8(xp[0], xp[1]);
#pragma unroll
            for (int nt = 0; nt < 2; ++nt)
                acc[mt][nt] = __builtin_amdgcn_mfma_f32_16x16x32_bf16(af, bv[nt],
                                                                      acc[mt][nt], 0, 0, 0);
        }
    }
    const float* bia = a.b[g];
    unsigned short* Xps = a.Xps[g];
    const int rb = tr * 64 + wr * 32;
#pragma unroll
    for (int nt = 0; nt < 2; ++nt) {
        int col = tc * 64 + wc * 32 + nt * 16 + lm;
        float bc = bia[col];
#pragma unroll
        for (int mt = 0; mt < 2; ++mt) {
            int rbase = rb + mt * 16 + lk * 4;
#pragma unroll
            for (int r = 0; r < 4; ++r) {
                int row = rbase + r;
                if (row < n) {
                    _Float16 h = (_Float16)(acc[mt][nt][r] + bc);
                    Xps[(size_t)row * F_DIM + col] = __builtin_bit_cast(unsigned short, h);
                }
            }
        }
    }
}

__device__ __forceinline__ void agg_unit(const GArgs& a, int g, int q, int n) {
    int node = q * 4 + (threadIdx.x >> 6);
    if (node >= n) return;
    const int l = threadIdx.x & 63;
    const int c = l & 15;
    const int hi = l >> 4;
    const uint4* Xp4 = (const uint4*)a.Xps[g];
    const unsigned short* sorted = a.sorted[g];
    const float* dinv = a.dinv[g];
    int cnt = a.cstore[g][node];
    int s = 0;
    float dv = 0.f;
    if (l < cnt) {
        s = (int)__builtin_nontemporal_load(&sorted[(size_t)node * CAP + l]);
        dv = dinv[s];
    }
    float a0 = 0.f, a1 = 0.f, a2 = 0.f, a3 = 0.f, a4 = 0.f, a5 = 0.f, a6 = 0.f, a7 = 0.f;
#define ACC8(V, W)                                                                 \
    {                                                                              \
        h2 p0 = __builtin_bit_cast(h2, (V).x);                                     \
        h2 p1 = __builtin_bit_cast(h2, (V).y);                                     \
        h2 p2 = __builtin_bit_cast(h2, (V).z);                                     \
        h2 p3 = __builtin_bit_cast(h2, (V).w);                                     \
        a0 += (float)p0.x * (W); a1 += (float)p0.y * (W);                          \
        a2 += (float)p1.x * (W); a3 += (float)p1.y * (W);                          \
        a4 += (float)p2.x * (W); a5 += (float)p2.y * (W);                          \
        a6 += (float)p3.x * (W); a7 += (float)p3.y * (W);                          \
    }
    for (int k = 0; k < cnt; k += 16) {
        int e0 = k + hi, e1 = k + 4 + hi, e2 = k + 8 + hi, e3 = k + 12 + hi;
        int s0 = __shfl(s, e0, 64);
        int s1 = __shfl(s, e1, 64);
        int s2 = __shfl(s, e2, 64);
        int s3 = __shfl(s, e3, 64);
        float w0 = __shfl(dv, e0, 64);
        float w1 = __shfl(dv, e1, 64);
        float w2 = __shfl(dv, e2, 64);
        float w3 = __shfl(dv, e3, 64);
        uint4 v0 = Xp4[(size_t)s0 * 16 + c];
        uint4 v1 = Xp4[(size_t)s1 * 16 + c];
        uint4 v2 = Xp4[(size_t)s2 * 16 + c];
        uint4 v3 = Xp4[(size_t)s3 * 16 + c];
        if (e0 >= cnt) w0 = 0.f;
        if (e1 >= cnt) w1 = 0.f;
        if (e2 >= cnt) w2 = 0.f;
        if (e3 >= cnt) w3 = 0.f;
        ACC8(v0, w0)
        ACC8(v1, w1)
        ACC8(v2, w2)
        ACC8(v3, w3)
    }
    a0 += __shfl_xor(a0, 16, 64); a0 += __shfl_xor(a0, 32, 64);
    a1 += __shfl_xor(a1, 16, 64); a1 += __shfl_xor(a1, 32, 64);
    a2 += __shfl_xor(a2, 16, 64); a2 += __shfl_xor(a2, 32, 64);
    a3 += __shfl_xor(a3, 16, 64); a3 += __shfl_xor(a3, 32, 64);
    a4 += __shfl_xor(a4, 16, 64); a4 += __shfl_xor(a4, 32, 64);
    a5 += __shfl_xor(a5, 16, 64); a5 += __shfl_xor(a5, 32, 64);
    a6 += __shfl_xor(a6, 16, 64); a6 += __shfl_xor(a6, 32, 64);
    a7 += __shfl_xor(a7, 16, 64); a7 += __shfl_xor(a7, 32, 64);
    float dd = dinv[node];
    uint4 v = Xp4[(size_t)node * 16 + c];
    ACC8(v, dd)
#undef ACC8
    if (hi == 0) {
        float* o = (float*)a.out[g] + (size_t)node * F_DIM + c * 8;
        *(float4*)(o + 0) = make_float4(a0 * dd, a1 * dd, a2 * dd, a3 * dd);
        *(float4*)(o + 4) = make_float4(a4 * dd, a5 * dd, a6 * dd, a7 * dd);
    }
}

__device__ __forceinline__ void spill_unit(const GArgs& a, int g, int i) {
    if (threadIdx.x >= 128) return;
    int s = a.spill[g][2 * i];
    int d = a.spill[g][2 * i + 1];
    float w = a.dinv[g][d] * a.dinv[g][s];
    int f = threadIdx.x;
    _Float16 h = __builtin_bit_cast(_Float16, a.Xps[g][(size_t)s * F_DIM + f]);
    unsafeAtomicAdd(&a.out[g][(size_t)d * F_DIM + f], w * (float)h);
}

// ================= cooperative mega-kernel ====================================
__global__ __launch_bounds__(256, 8) void mega_kernel(GArgs a, int E, int n) {
    cg::grid_group grid = cg::this_grid();
    const int G = gridDim.x, b = blockIdx.x, t = threadIdx.x;
    const int nbin = a.nbin;

    // P0: init (bincur, spill_n, Wtb)
    {
        int per = (nbin > 2048) ? nbin : 2048;
        for (int u = b * 256 + t; u < NG * per; u += G * 256)
            init_unit(a, u / per, u % per);
    }
    grid.sync();

    const int nChunk = (E + 4095) / 4096;
    const int NA = NG * nChunk;
    const int GT = ((n + 63) >> 6) * 2;
    const int NGm = NG * GT;
    const int half = (NGm + 1) / 2;
    int split = (G * 2) / 5;
    if (split < 1) split = 1;
    if (split >= G) split = G - 1;

    // P1: binA || gemm first half
    if (b < split) {
        for (int u = b; u < NA; u += split) binA_unit(a, u / nChunk, u % nChunk, E);
    } else {
        for (int u = b - split; u < half; u += (G - split)) gemm_unit(a, u / GT, u % GT, n);
    }
    grid.sync();

    // P2: binB || gemm second half
    if (b < split) {
        for (int u = b; u < NG * nbin; u += split) binB_unit(a, u / nbin, u % nbin, n);
    } else {
        for (int u = half + (b - split); u < NGm; u += (G - split)) gemm_unit(a, u / GT, u % GT, n);
    }
    grid.sync();

    // P3: agg
    const int qper = (n + 3) / 4;
    for (int u = b; u < NG * qper; u += G) agg_unit(a, u / qper, u % qper, n);
    grid.sync();

    // P4: spill
    for (int g = 0; g < NG; ++g) {
        int ns = min(a.spill_n[g][0], SPILL_CAP);
        for (int i = b; i < ns; i += G) spill_unit(a, g, i);
    }
}

// ================= fallback standalone kernels ================================
__global__ __launch_bounds__(256) void init_kernel(GArgs a, int E, int n) {
    init_unit(a, blockIdx.y, blockIdx.x * 256 + threadIdx.x);
}
__global__ __launch_bounds__(256) void binA_kernel(GArgs a, int E, int n) {
    binA_unit(a, blockIdx.y, blockIdx.x, E);
}
__global__ __launch_bounds__(256) void binB_kernel(GArgs a, int E, int n) {
    binB_unit(a, blockIdx.y, blockIdx.x, n);
}
__global__ __launch_bounds__(256) void gemm_kernel(GArgs a, int E, int n) {
    gemm_unit(a, blockIdx.y, blockIdx.x, n);
}
__global__ __launch_bounds__(256) void agg_kernel(GArgs a, int E, int n) {
    agg_unit(a, blockIdx.y, blockIdx.x, n);
}
__global__ __launch_bounds__(256) void spill_kernel(GArgs a, int E, int n) {
    int g = blockIdx.y;
    int ns = min(a.spill_n[g][0], SPILL_CAP);
    for (int i = blockIdx.x; i < ns; i += gridDim.x) spill_unit(a, g, i);
}

extern "C" void kernel_launch(void* const* d_in, const int* in_sizes, int n_in,
                              void* d_out, int out_size, void* d_ws, size_t ws_size,
                              hipStream_t stream) {
    const float* Xin[NG] = {(const float*)d_in[0], (const float*)d_in[1], (const float*)d_in[2]};
    const int* ei[NG] = {(const int*)d_in[3], (const int*)d_in[4], (const int*)d_in[5]};
    const float* Wk[NG] = {(const float*)d_in[6], (const float*)d_in[8], (const float*)d_in[10]};
    const float* bk[NG] = {(const float*)d_in[7], (const float*)d_in[9], (const float*)d_in[11]};

    const int N = in_sizes[0] / F_DIM;  // 50000
    const int E = in_sizes[3] / 2;      // 800000
    float* out = (float*)d_out;

    const int nbin = (N + 255) >> 8;
    const int bincap = E / nbin + E / (3 * nbin) + 256;

    const size_t xps_b = (size_t)N * F_DIM * 2;
    const size_t sorted_b = (size_t)N * CAP * 2;
    const size_t wtb_b = (size_t)16 * 128 * 8 * 2;
    const size_t binbuf_b = (size_t)nbin * bincap * 4;
    const size_t nb = (size_t)N * 4;
    const size_t bincur_b = ((size_t)nbin * 4 + 255) / 256 * 256;
    const size_t spill_b = (size_t)SPILL_CAP * 8 + 64;
    const size_t per = ((xps_b + sorted_b + wtb_b + binbuf_b + 2 * nb + bincur_b + spill_b
                         + 255) / 256) * 256;
    const bool multi = ws_size >= (size_t)NG * per;
    char* base = (char*)d_ws;

    GArgs a;
    a.nbin = nbin;
    a.bincap = bincap;
    for (int r = 0; r < NG; ++r) {
        char* s = base + (size_t)(multi ? r : 0) * per;
        size_t off = 0;
        a.Xps[r] = (unsigned short*)(s + off); off += xps_b;
        a.sorted[r] = (unsigned short*)(s + off); off += sorted_b;
        a.Wtb[r] = (unsigned short*)(s + off); off += wtb_b;
        a.binbuf[r] = (int*)(s + off); off += binbuf_b;
        a.cstore[r] = (int*)(s + off); off += nb;
        a.dinv[r] = (float*)(s + off); off += nb;
        a.bincur[r] = (int*)(s + off); off += bincur_b;
        a.spill[r] = (int*)(s + off);
        a.spill_n[r] = (int*)(s + off + spill_b - 64);
        a.src[r] = ei[r];
        a.dst[r] = ei[r] + E;
        a.X[r] = Xin[r];
        a.W[r] = Wk[r];
        a.b[r] = bk[r];
        a.out[r] = out + (size_t)r * N * F_DIM;
    }

    const dim3 blk(256);
    const int nChunk = (E + 4095) / 4096;
    const int GT = ((N + 63) >> 6) * 2;
    const int qper = (N + 3) / 4;

    // ---- try cooperative mega-kernel (only valid when workspace holds all 3) --
    bool coop_done = false;
    if (multi) {
        hipDeviceProp_t prop;
        int dev = 0;
        if (hipGetDevice(&dev) == hipSuccess &&
            hipGetDeviceProperties(&prop, dev) == hipSuccess &&
            prop.cooperativeLaunch) {
            int maxb = 0;
            if (hipOccupancyMaxActiveBlocksPerMultiprocessor(&maxb, mega_kernel, 256, 0)
                    == hipSuccess && maxb > 0) {
                int G = maxb * prop.multiProcessorCount;
                if (G > NG * qper) G = NG * qper;
                if (G >= 16) {
                    int E2 = E, N2 = N;
                    void* args[] = {(void*)&a, (void*)&E2, (void*)&N2};
                    if (hipLaunchCooperativeKernel((void*)mega_kernel, dim3(G), blk,
                                                   args, 0, stream) == hipSuccess)
                        coop_done = true;
                }
            }
        }
    }

    if (!coop_done) {
        // fallback: proven multi-launch path (identical math)
        const int initx = (((nbin > 2048 ? nbin : 2048) + 255) / 256);
        if (multi) {
            init_kernel<<<dim3(initx, NG), blk, 0, stream>>>(a, E, N);
            binA_kernel<<<dim3(nChunk, NG), blk, 0, stream>>>(a, E, N);
            binB_kernel<<<dim3(nbin, NG), blk, 0, stream>>>(a, E, N);
            gemm_kernel<<<dim3(GT, NG), blk, 0, stream>>>(a, E, N);
            agg_kernel<<<dim3(qper, NG), blk, 0, stream>>>(a, E, N);
            spill_kernel<<<dim3(16, NG), blk, 0, stream>>>(a, E, N);
        } else {
            for (int g = 0; g < NG; ++g) {
                GArgs ag = a;  // slot-0 workspace reused; rebind graph g into slot 0
                ag.src[0] = a.src[g]; ag.dst[0] = a.dst[g];
                ag.X[0] = a.X[g]; ag.W[0] = a.W[g]; ag.b[0] = a.b[g];
                ag.out[0] = a.out[g];
                init_kernel<<<dim3(initx, 1), blk, 0, stream>>>(ag, E, N);
                binA_kernel<<<dim3(nChunk, 1), blk, 0, stream>>>(ag, E, N);
                binB_kernel<<<dim3(nbin, 1), blk, 0, stream>>>(ag, E, N);
                gemm_kernel<<<dim3(GT, 1), blk, 0, stream>>>(ag, E, N);
                agg_kernel<<<dim3(qper, 1), blk, 0, stream>>>(ag, E, N);
                spill_kernel<<<dim3(16, 1), blk, 0, stream>>>(ag, E, N);
            }
        }
    }
}

// Round 19
// 175.437 us; speedup vs baseline: 4.2695x; 4.2695x over previous
//
#include <hip/hip_runtime.h>

#define F_DIM 128
#define NG 3
#define AEPT 16      // edges per thread in phase A
#define CAP 48       // fixed per-node CSR capacity (mean deg 16, max ~35)
#define MAXBIN 256
#define SPILL_CAP 8192

typedef __attribute__((ext_vector_type(8))) short short8_t;
typedef __attribute__((ext_vector_type(4))) float f32x4;
typedef _Float16 h2 __attribute__((ext_vector_type(2)));

__device__ __forceinline__ unsigned short f2bf(float f) {
    unsigned int x = __float_as_uint(f);
    unsigned int r = x + 0x7fffu + ((x >> 16) & 1u);  // RNE
    return (unsigned short)(r >> 16);
}

__device__ __forceinline__ short8_t cvt8(float4 x0, float4 x1) {
    union { short8_t s; uint4 u; } pk;
    pk.u.x = (unsigned)f2bf(x0.x) | ((unsigned)f2bf(x0.y) << 16);
    pk.u.y = (unsigned)f2bf(x0.z) | ((unsigned)f2bf(x0.w) << 16);
    pk.u.z = (unsigned)f2bf(x1.x) | ((unsigned)f2bf(x1.y) << 16);
    pk.u.w = (unsigned)f2bf(x1.z) | ((unsigned)f2bf(x1.w) << 16);
    return pk.s;
}

struct GArgs {
    const int* src[NG]; const int* dst[NG];
    const float* X[NG]; const float* W[NG]; const float* b[NG];
    float* out[NG];
    unsigned short* Xps[NG];   // FP16 row-major [N][128], RAW (X@W+b, unscaled)
    unsigned short* sorted[NG];// [N*CAP] u16 src indices
    unsigned short* Wtb[NG];   // bf16 W^T in B-frag order [16 kg][128 col][8]
    int* binbuf[NG];           // [nbin*BINCAP] packed (dlocal<<16)|src
    int* bincur[NG];           // [nbin] global bin cursors (init bin*BINCAP)
    int* cstore[NG];           // [N] stored counts (<=CAP)
    float* dinv[NG];           // [N]
    int* spill[NG];            // [SPILL_CAP*2] (src,dst) pairs
    int* spill_n[NG];          // [1]
    int nbin, bincap;
};

// ---- init: bincur, spill_n, AND prew (W -> Wtb bf16 B-frag order) ------------
__global__ __launch_bounds__(256) void init_kernel(GArgs a, int g0) {
    int g = g0 + blockIdx.y;
    for (int i = threadIdx.x; i < a.nbin; i += 256) a.bincur[g][i] = i * a.bincap;
    if (threadIdx.x == 0) a.spill_n[g][0] = 0;
    const float* W = a.W[g];
    unsigned short* Wtb = a.Wtb[g];
    for (int i = threadIdx.x; i < 16 * 128; i += 256) {
        int kg = i >> 7, c = i & 127;
        const float* wp = W + (size_t)(kg * 8) * F_DIM + c;
        uint4 pk;
        pk.x = (unsigned)f2bf(wp[0])   | ((unsigned)f2bf(wp[128]) << 16);
        pk.y = (unsigned)f2bf(wp[256]) | ((unsigned)f2bf(wp[384]) << 16);
        pk.z = (unsigned)f2bf(wp[512]) | ((unsigned)f2bf(wp[640]) << 16);
        pk.w = (unsigned)f2bf(wp[768]) | ((unsigned)f2bf(wp[896]) << 16);
        *(uint4*)(Wtb + (size_t)i * 8) = pk;
    }
}

// ---- binA: coarse radix partition (bin = dst>>8), LDS counting ---------------
__global__ __launch_bounds__(256) void binA_kernel(GArgs a, int g0, int E) {
    int g = g0 + blockIdx.y;
    __shared__ int cnt[MAXBIN];
    __shared__ int lcur[MAXBIN];
    const int t = threadIdx.x;
    const int nbin = a.nbin, bincap = a.bincap;
    for (int i = t; i < nbin; i += 256) cnt[i] = 0;
    __syncthreads();
    const int* dst = a.dst[g];
    const int* src = a.src[g];
    const int base = blockIdx.x * (256 * AEPT) + t;
    int dd[AEPT], sv[AEPT];
#pragma unroll
    for (int i = 0; i < AEPT; ++i) {
        int e = base + i * 256;
        int ec = (e < E) ? e : 0;
        dd[i] = __builtin_nontemporal_load(&dst[ec]);
        sv[i] = __builtin_nontemporal_load(&src[ec]);
        if (e < E) atomicAdd(&cnt[dd[i] >> 8], 1);
    }
    __syncthreads();
    for (int i = t; i < nbin; i += 256) {
        int c = cnt[i];
        lcur[i] = c ? atomicAdd(&a.bincur[g][i], c) : 0;
    }
    __syncthreads();
    int* binbuf = a.binbuf[g];
#pragma unroll
    for (int i = 0; i < AEPT; ++i) {
        int e = base + i * 256;
        if (e < E) {
            int bin = dd[i] >> 8;
            int pos = atomicAdd(&lcur[bin], 1);
            if (pos < (bin + 1) * bincap) {
                binbuf[pos] = ((dd[i] & 255) << 16) | sv[i];
            } else {
                int sp = atomicAdd(a.spill_n[g], 1);
                if (sp < SPILL_CAP) {
                    a.spill[g][2 * sp] = sv[i];
                    a.spill[g][2 * sp + 1] = dd[i];
                }
            }
        }
    }
}

// ---- binB: fine binning within a bin; LDS tickets only -----------------------
__global__ __launch_bounds__(256) void binB_kernel(GArgs a, int g0, int n) {
    int g = g0 + blockIdx.y;
    int bin = blockIdx.x;
    const int t = threadIdx.x;
    __shared__ int cnt[256];
    cnt[t] = 0;
    __syncthreads();
    const int bincap = a.bincap;
    int used = a.bincur[g][bin] - bin * bincap;
    int rd = min(used, bincap);
    const int* bb = a.binbuf[g] + bin * bincap;
    unsigned short* sorted = a.sorted[g];
    for (int j = t; j < rd; j += 256) {
        int u = bb[j];
        int dl = u >> 16;
        int s = u & 0xffff;
        int tk = atomicAdd(&cnt[dl], 1);
        int d = (bin << 8) + dl;
        if (tk < CAP) {
            sorted[d * CAP + tk] = (unsigned short)s;
        } else {
            int sp = atomicAdd(a.spill_n[g], 1);
            if (sp < SPILL_CAP) {
                a.spill[g][2 * sp] = s;
                a.spill[g][2 * sp + 1] = d;
            }
        }
    }
    __syncthreads();
    int d = (bin << 8) + t;
    if (d < n) {
        int deg = cnt[t];
        a.cstore[g][d] = min(deg, CAP);
        a.dinv[g][d] = rsqrtf((float)deg + 1.0f);
    }
}

// ---- MFMA bf16 GEMM, barrier-free & LDS-free; 64x128 block tile --------------
// 4 waves (2x2), wave tile 32x64 (2x4 of 16x16) -> 782 blocks/graph (2x TLP).
// A-frags global->reg + in-reg bf16 cvt; B-frags from L2-hot Wtb.
// Output Xps is FP16 raw (X@W+b).
__global__ __launch_bounds__(256) void gemm_kernel(GArgs a, int g0, int n) {
    int g = g0 + blockIdx.y;
    const int t = threadIdx.x;
    const int l = t & 63;
    const int wv = t >> 6;
    const int wr = wv >> 1, wc = wv & 1;
    const int lm = l & 15, lk = l >> 4;
    const int rowA = blockIdx.x * 64 + wr * 32 + lm;  // A-frag row (+mt*16)
    const float* X = a.X[g];
    const unsigned short* Wtb = a.Wtb[g];

    f32x4 acc[2][4] = {};
#pragma unroll
    for (int ks = 0; ks < 4; ++ks) {
        short8_t bv[4];
#pragma unroll
        for (int nt = 0; nt < 4; ++nt) {
            int col = wc * 64 + nt * 16 + lm;
            bv[nt] = *(const short8_t*)(Wtb + ((size_t)((ks * 4 + lk) * 128 + col)) * 8);
        }
        float4 xr[2][2];
#pragma unroll
        for (int mt = 0; mt < 2; ++mt) {
            int row = rowA + mt * 16;
            row = row < n ? row : n - 1;  // clamp: A-row only affects its own C-row
            const float4* xp = (const float4*)(X + (size_t)row * F_DIM + ks * 32 + lk * 8);
            xr[mt][0] = xp[0];
            xr[mt][1] = xp[1];
        }
#pragma unroll
        for (int mt = 0; mt < 2; ++mt) {
            short8_t af = cvt8(xr[mt][0], xr[mt][1]);
#pragma unroll
            for (int nt = 0; nt < 4; ++nt)
                acc[mt][nt] = __builtin_amdgcn_mfma_f32_16x16x32_bf16(af, bv[nt],
                                                                      acc[mt][nt], 0, 0, 0);
        }
    }

    const float* bia = a.b[g];
    unsigned short* Xps = a.Xps[g];
    const int rb = blockIdx.x * 64 + wr * 32;
#pragma unroll
    for (int nt = 0; nt < 4; ++nt) {
        int col = wc * 64 + nt * 16 + lm;
        float bc = bia[col];
#pragma unroll
        for (int mt = 0; mt < 2; ++mt) {
            int rbase = rb + mt * 16 + lk * 4;
#pragma unroll
            for (int r = 0; r < 4; ++r) {
                int row = rbase + r;
                if (row < n) {
                    _Float16 h = (_Float16)(acc[mt][nt][r] + bc);
                    Xps[(size_t)row * F_DIM + col] = __builtin_bit_cast(unsigned short, h);
                }
            }
        }
    }
}

// ---- aggregation (fused): wave = node; 16 lanes x dwordx4; 16 rows in flight -
// Xps is FP16 raw; per-row weight dinv[s] applied via (float)h * w -> the
// compiler emits v_fma_mix_f32 (extraction folded into fma).
__global__ __launch_bounds__(256) void agg_kernel(GArgs a, int g0, int n) {
    int g = g0 + blockIdx.y;
    int wave = (blockIdx.x * 256 + threadIdx.x) >> 6;
    if (wave >= n) return;
    const int l = threadIdx.x & 63;
    const int c = l & 15;     // 16B column (features c*8 .. c*8+7)
    const int hi = l >> 4;    // edge slot 0..3
    const uint4* Xp4 = (const uint4*)a.Xps[g];  // 16 uint4 per row
    const unsigned short* sorted = a.sorted[g];
    const float* dinv = a.dinv[g];
    int cnt = a.cstore[g][wave];
    int s = 0;
    float dv = 0.f;
    if (l < cnt) {
        s = (int)__builtin_nontemporal_load(&sorted[(size_t)wave * CAP + l]);
        dv = dinv[s];
    }
    float a0 = 0.f, a1 = 0.f, a2 = 0.f, a3 = 0.f, a4 = 0.f, a5 = 0.f, a6 = 0.f, a7 = 0.f;
#define ACC8(V, W)                                                                 \
    {                                                                              \
        h2 p0 = __builtin_bit_cast(h2, (V).x);                                     \
        h2 p1 = __builtin_bit_cast(h2, (V).y);                                     \
        h2 p2 = __builtin_bit_cast(h2, (V).z);                                     \
        h2 p3 = __builtin_bit_cast(h2, (V).w);                                     \
        a0 += (float)p0.x * (W); a1 += (float)p0.y * (W);                          \
        a2 += (float)p1.x * (W); a3 += (float)p1.y * (W);                          \
        a4 += (float)p2.x * (W); a5 += (float)p2.y * (W);                          \
        a6 += (float)p3.x * (W); a7 += (float)p3.y * (W);                          \
    }
    for (int k = 0; k < cnt; k += 16) {
        int e0 = k + hi, e1 = k + 4 + hi, e2 = k + 8 + hi, e3 = k + 12 + hi;  // < CAP
        int s0 = __shfl(s, e0, 64);
        int s1 = __shfl(s, e1, 64);
        int s2 = __shfl(s, e2, 64);
        int s3 = __shfl(s, e3, 64);
        float w0 = __shfl(dv, e0, 64);
        float w1 = __shfl(dv, e1, 64);
        float w2 = __shfl(dv, e2, 64);
        float w3 = __shfl(dv, e3, 64);
        uint4 v0 = Xp4[(size_t)s0 * 16 + c];
        uint4 v1 = Xp4[(size_t)s1 * 16 + c];
        uint4 v2 = Xp4[(size_t)s2 * 16 + c];
        uint4 v3 = Xp4[(size_t)s3 * 16 + c];
        if (e0 >= cnt) w0 = 0.f;
        if (e1 >= cnt) w1 = 0.f;
        if (e2 >= cnt) w2 = 0.f;
        if (e3 >= cnt) w3 = 0.f;
        ACC8(v0, w0)
        ACC8(v1, w1)
        ACC8(v2, w2)
        ACC8(v3, w3)
    }
    a0 += __shfl_xor(a0, 16, 64); a0 += __shfl_xor(a0, 32, 64);
    a1 += __shfl_xor(a1, 16, 64); a1 += __shfl_xor(a1, 32, 64);
    a2 += __shfl_xor(a2, 16, 64); a2 += __shfl_xor(a2, 32, 64);
    a3 += __shfl_xor(a3, 16, 64); a3 += __shfl_xor(a3, 32, 64);
    a4 += __shfl_xor(a4, 16, 64); a4 += __shfl_xor(a4, 32, 64);
    a5 += __shfl_xor(a5, 16, 64); a5 += __shfl_xor(a5, 32, 64);
    a6 += __shfl_xor(a6, 16, 64); a6 += __shfl_xor(a6, 32, 64);
    a7 += __shfl_xor(a7, 16, 64); a7 += __shfl_xor(a7, 32, 64);
    // self-loop term (weight dinv[wave]) + final dinv[wave] scale
    float dd = dinv[wave];
    uint4 v = Xp4[(size_t)wave * 16 + c];
    ACC8(v, dd)
#undef ACC8
    if (hi == 0) {
        float* o = (float*)a.out[g] + (size_t)wave * F_DIM + c * 8;
        *(float4*)(o + 0) = make_float4(a0 * dd, a1 * dd, a2 * dd, a3 * dd);
        *(float4*)(o + 4) = make_float4(a4 * dd, a5 * dd, a6 * dd, a7 * dd);
    }
}

// ---- spill cleanup: out[d] += dinv[d]*dinv[s] * Xraw[s] (fp16) ---------------
__global__ __launch_bounds__(128) void spill_kernel(GArgs a, int g0) {
    int g = g0 + blockIdx.y;
    int ns = min(a.spill_n[g][0], SPILL_CAP);
    const unsigned short* Xps = a.Xps[g];
    const float* dinv = a.dinv[g];
    float* out = a.out[g];
    for (int i = blockIdx.x; i < ns; i += gridDim.x) {
        int s = a.spill[g][2 * i];
        int d = a.spill[g][2 * i + 1];
        float w = dinv[d] * dinv[s];
        int f = threadIdx.x;
        _Float16 h = __builtin_bit_cast(_Float16, Xps[(size_t)s * F_DIM + f]);
        unsafeAtomicAdd(&out[(size_t)d * F_DIM + f], w * (float)h);
    }
}

extern "C" void kernel_launch(void* const* d_in, const int* in_sizes, int n_in,
                              void* d_out, int out_size, void* d_ws, size_t ws_size,
                              hipStream_t stream) {
    const float* Xin[NG] = {(const float*)d_in[0], (const float*)d_in[1], (const float*)d_in[2]};
    const int* ei[NG] = {(const int*)d_in[3], (const int*)d_in[4], (const int*)d_in[5]};
    const float* Wk[NG] = {(const float*)d_in[6], (const float*)d_in[8], (const float*)d_in[10]};
    const float* bk[NG] = {(const float*)d_in[7], (const float*)d_in[9], (const float*)d_in[11]};

    const int N = in_sizes[0] / F_DIM;  // 50000
    const int E = in_sizes[3] / 2;      // 800000
    float* out = (float*)d_out;

    const int nbin = (N + 255) >> 8;                    // 196
    const int bincap = E / nbin + E / (3 * nbin) + 256; // ~5700

    const size_t xps_b = (size_t)N * F_DIM * 2;         // fp16
    const size_t sorted_b = (size_t)N * CAP * 2;        // u16
    const size_t wtb_b = (size_t)16 * 128 * 8 * 2;      // 32KB
    const size_t binbuf_b = (size_t)nbin * bincap * 4;
    const size_t nb = (size_t)N * 4;
    const size_t bincur_b = ((size_t)nbin * 4 + 255) / 256 * 256;
    const size_t spill_b = (size_t)SPILL_CAP * 8 + 64;
    const size_t per = ((xps_b + sorted_b + wtb_b + binbuf_b + 2 * nb + bincur_b + spill_b
                         + 255) / 256) * 256;
    const bool fused = ws_size >= (size_t)NG * per;
    char* base = (char*)d_ws;

    GArgs a;
    a.nbin = nbin;
    a.bincap = bincap;
    for (int r = 0; r < NG; ++r) {
        char* s = base + (size_t)(fused ? r : 0) * per;
        size_t off = 0;
        a.Xps[r] = (unsigned short*)(s + off); off += xps_b;
        a.sorted[r] = (unsigned short*)(s + off); off += sorted_b;
        a.Wtb[r] = (unsigned short*)(s + off); off += wtb_b;
        a.binbuf[r] = (int*)(s + off); off += binbuf_b;
        a.cstore[r] = (int*)(s + off); off += nb;
        a.dinv[r] = (float*)(s + off); off += nb;
        a.bincur[r] = (int*)(s + off); off += bincur_b;
        a.spill[r] = (int*)(s + off);
        a.spill_n[r] = (int*)(s + off + spill_b - 64);
        a.src[r] = ei[r];
        a.dst[r] = ei[r] + E;
        a.X[r] = Xin[r];
        a.W[r] = Wk[r];
        a.b[r] = bk[r];
        a.out[r] = out + (size_t)r * N * F_DIM;
    }

    const dim3 blk(256);
    const int gAe = (E + 256 * AEPT - 1) / (256 * AEPT);  // binA blocks
    const int gR = (N + 63) / 64;                          // gemm blocks (64-row tile)
    const int gG = (N * 64 + 255) / 256;

    if (fused) {
        init_kernel<<<dim3(1, NG), blk, 0, stream>>>(a, 0);
        binA_kernel<<<dim3(gAe, NG), blk, 0, stream>>>(a, 0, E);
        binB_kernel<<<dim3(nbin, NG), blk, 0, stream>>>(a, 0, N);
        gemm_kernel<<<dim3(gR, NG), blk, 0, stream>>>(a, 0, N);
        agg_kernel<<<dim3(gG, NG), blk, 0, stream>>>(a, 0, N);
        spill_kernel<<<dim3(16, NG), dim3(128), 0, stream>>>(a, 0);
    } else {
        for (int g = 0; g < NG; ++g) {
            init_kernel<<<dim3(1, 1), blk, 0, stream>>>(a, g);
            binA_kernel<<<dim3(gAe, 1), blk, 0, stream>>>(a, g, E);
            binB_kernel<<<dim3(nbin, 1), blk, 0, stream>>>(a, g, N);
            gemm_kernel<<<dim3(gR, 1), blk, 0, stream>>>(a, g, N);
            agg_kernel<<<dim3(gG, 1), blk, 0, stream>>>(a, g, N);
            spill_kernel<<<dim3(16, 1), dim3(128), 0, stream>>>(a, g);
        }
    }
}